// Round 7
// baseline (465.576 us; speedup 1.0000x reference)
//
#include <hip/hip_runtime.h>
#include <hip/hip_bf16.h>

// ---------------------------------------------------------------------------
// NaSwinAttention on MI355X.
// Static problem geometry:
//   T=10,H=45,W=80 -> N_VID=36000, D=512, HEADS=4, HD=128, TXT=64
//   windows: wt=5, wh=9, ww=16 ; nt=2, nh=5, nw=5 -> 50 windows x 720 tokens
//   window id  w = iw*10 + ih*2 + it   (it fastest)
//   pos in win p = dt*144 + dh*16 + dw
//   token      n = (it*5+dt)*3600 + (ih*9+dh)*80 + iw*16 + dw
//   seq per window = 720 + 64 txt = 784, padded to 832 (13*64)
//
// Vt global layout is POSITION-PERMUTED: within each 32-aligned pos chunk,
// physical index e holds logical pos (e>>3)*4 + (e&3) + ((e>>2)&1)*16, so
// k_attn's b128 read at phys [quad*8..+7] yields logical keys
// {quad*4+0..3, 16+quad*4+0..3} = the sigma-order used by the register-P
// PV contraction. Inverse (4-aligned run start l0):
//   phys = (l0 & ~31) + ((l0&15)>>2)*8 + ((l0>>4)&1)*4
//
// R1: attn 2-phase pipeline + dead-wave skip + exp2 (115 us; gain==skip).
// R2: FAILED: 8-wave attn blocks -> barrier lockstep, 145 us. Reverted.
// R3: 256x256 QKV GEMM w/ counted vmcnt pipeline (T4) + swizzle (T2): -12 us.
// R4/R5: FAILED: attn 1-deep sw-pipeline -> VGPR 96->140, occupancy halved,
//     163 us. Reverted; attn R1 structure is a measured local optimum.
// R6: out-GEMM ported to 256x256 counted-vmcnt structure: -12.5 us (438 us).
// R7: (a) k_ropegather: RoPE cos/sin from precomputed per-axis tables
//     (3160 float2, filled by one extra k_prep block) instead of per-element
//     exp2f+__sincosf (Appendix-B trig-table fix; ~96 TRANS ops/thread -> 8
//     float2 L1-resident loads). (b) k_attn split into 704+696-block
//     dispatches (multiple of 8 keeps XCD pairing) so other kernels >57 us
//     become visible in top-5 and inter-dispatch gaps are measurable.
//     Note: attn b128 fragment reads cover a dense 1KB -> the 8.08M bank-
//     conflict count is the structural floor; swizzle cannot help (analyzed).
// ---------------------------------------------------------------------------

typedef unsigned short u16;
typedef unsigned int   u32;
typedef float v4f __attribute__((ext_vector_type(4)));
typedef short v8s __attribute__((ext_vector_type(8)));

#define N_VID    36000
#define MPAD     36096        // 282*128 = 141*256
#define DM       512
#define NW       50
#define WSZ      720
#define SEQ      784
#define SP       832          // padded seq (13*64)
// 1/sqrt(128) * log2(e): Q pre-scale so attn uses exp2 directly
#define QK_SCALE_L2E 0.12751743f
#define L2THETA  13.287712379549449f   // log2(10000)
// rope table offsets: t-axis [10][16], h-axis [45][24], w-axis [80][24]
#define TBL_H    160
#define TBL_W    1240
#define TBL_N    3160

union U8 { uint4 u; u16 s[8]; };

__device__ __forceinline__ u16 f2b(float f) {
  u32 u = __builtin_bit_cast(u32, f);
  u32 r = (u + 0x7FFFu + ((u >> 16) & 1u)) >> 16;
  return (u16)r;
}
__device__ __forceinline__ float b2f(u16 h) {
  u32 u = ((u32)h) << 16;
  return __builtin_bit_cast(float, u);
}
// pack hi16(lo),hi16(hi) -> u32 (bf16 truncation pack, 1 instr)
__device__ __forceinline__ u32 pkhi(float lo, float hi) {
  return __builtin_amdgcn_perm(__builtin_bit_cast(u32, hi),
                               __builtin_bit_cast(u32, lo), 0x07060302u);
}
// physical index of a 4-aligned logical-position run start (Vt permutation)
__device__ __forceinline__ int vperm4(int l0) {
  return (l0 & ~31) + (((l0 & 15) >> 2) << 3) + (((l0 >> 4) & 1) << 2);
}

__device__ __forceinline__ void gload_lds16(const void* g, void* l) {
  __builtin_amdgcn_global_load_lds(
      (const __attribute__((address_space(1))) void*)g,
      (__attribute__((address_space(3))) void*)l,
      16, 0, 0);
}

// ---------------------------------------------------------------------------
// K0: fused prep. blocks 0..9087: fp32->bf16 convert (vid padded to MPAD,
// txt padded to 256 rows). blocks 9088..9535: weight transpose
// fp32[K][N]->bf16[N][K]. block 9536: rope cos/sin tables.
__global__ __launch_bounds__(256) void k_prep(const float* __restrict__ vid,
                                              const float* __restrict__ txt,
                                              u16* __restrict__ vid_b,
                                              u16* __restrict__ txt_b,
                                              const float* __restrict__ wqv,
                                              const float* __restrict__ wqt,
                                              const float* __restrict__ wov,
                                              u16* __restrict__ o0,
                                              u16* __restrict__ o1,
                                              u16* __restrict__ o2,
                                              float2* __restrict__ tbl) {
  __shared__ u16 lt[64 * 72];
  int t = threadIdx.x;
  if (blockIdx.x < 9088) {
    int id  = blockIdx.x * 256 + t;
    int row = id >> 6, oct = id & 63;
    U8 o;
    if (row < MPAD) {
      if (row < N_VID) {
        const float* s = vid + (size_t)row * DM + oct * 8;
        float4 a = *(const float4*)s, b = *(const float4*)(s + 4);
        o.s[0]=f2b(a.x); o.s[1]=f2b(a.y); o.s[2]=f2b(a.z); o.s[3]=f2b(a.w);
        o.s[4]=f2b(b.x); o.s[5]=f2b(b.y); o.s[6]=f2b(b.z); o.s[7]=f2b(b.w);
      } else { o.u = make_uint4(0,0,0,0); }
      *(uint4*)&vid_b[(size_t)row * DM + oct * 8] = o.u;
    } else {
      int tr = row - MPAD;
      if (tr >= 256) return;
      if (tr < 64) {
        const float* s = txt + (size_t)tr * DM + oct * 8;
        float4 a = *(const float4*)s, b = *(const float4*)(s + 4);
        o.s[0]=f2b(a.x); o.s[1]=f2b(a.y); o.s[2]=f2b(a.z); o.s[3]=f2b(a.w);
        o.s[4]=f2b(b.x); o.s[5]=f2b(b.y); o.s[6]=f2b(b.z); o.s[7]=f2b(b.w);
      } else { o.u = make_uint4(0,0,0,0); }
      *(uint4*)&txt_b[(size_t)tr * DM + oct * 8] = o.u;
    }
    return;
  }
  // ---- transpose / table branch ----
  int b = blockIdx.x - 9088;
  if (b == 448) {
    // rope tables: entry i -> (pos, freq k, axis dinv); cos/sin of pos*inv
    for (int i = t; i < TBL_N; i += 256) {
      int pos, k; float dinv;
      if (i < TBL_H)      { pos = i >> 4;             k = i & 15;          dinv = 1.f / 32.f; }
      else if (i < TBL_W) { int j = i - TBL_H;  pos = j / 24; k = j % 24;  dinv = 1.f / 48.f; }
      else                { int j = i - TBL_W;  pos = j / 24; k = j % 24;  dinv = 1.f / 48.f; }
      float inv = exp2f(-2.f * (float)k * dinv * L2THETA);
      float ang = (float)pos * inv;
      tbl[i] = make_float2(cosf(ang), sinf(ang));
    }
    return;
  }
  const float* src; u16* dst; int N; int tb;
  if (b < 192)      { src = wqv; dst = o0; N = 1536; tb = b; }
  else if (b < 384) { src = wqt; dst = o1; N = 1536; tb = b - 192; }
  else              { src = wov; dst = o2; N = 512;  tb = b - 384; }
  int kt = tb & 7, nt = tb >> 3;
  int k0 = kt * 64, n0 = nt * 64;
#pragma unroll
  for (int pass = 0; pass < 16; ++pass) {
    int kl = pass * 4 + (t >> 6), nl = t & 63;
    float v = src[(size_t)(k0 + kl) * N + n0 + nl];
    lt[nl * 72 + kl] = f2b(v);
  }
  __syncthreads();
#pragma unroll
  for (int pass = 0; pass < 2; ++pass) {
    int slot = pass * 256 + t;
    int nr = slot >> 3, ko = slot & 7;
    U8 o;
#pragma unroll
    for (int j = 0; j < 8; ++j) o.s[j] = lt[nr * 72 + ko * 8 + j];
    *(uint4*)&dst[(size_t)(n0 + nr) * 512 + k0 + ko * 8] = o.u;
  }
}

// ---------------------------------------------------------------------------
// 256x256 tile GEMM body (R3-proven): BK=64, 8 waves (2M x 4N), 512 threads,
// K=512 fixed (8 K-tiles). Double-buffered LDS (128 KB), raw s_barrier +
// counted s_waitcnt vmcnt(8): tile kt+2's 8 loads stay in flight across both
// barriers. XOR col-block swizzle (involution) on global source + ds_read.
// C row stride NSTR; rows >= Mstore masked (f32 or bf16 out via F32OUT).
template <int NSTR, int F32OUT>
__device__ __forceinline__ void gemm256(const u16* __restrict__ Ap,
                                        const u16* __restrict__ Bp,
                                        void* __restrict__ Cp,
                                        int m0, int n0, int Mstore) {
  __shared__ u16 lA[2][256 * 64];
  __shared__ u16 lB[2][256 * 64];
  int t = threadIdx.x, wv = t >> 6, L = t & 63;
  int wm = wv >> 2, wn = wv & 3;                 // 2 x 4 wave grid
  int colL = L & 15, quad = L >> 4;

  // staging: per wave 4 calls/operand, each fills 8 rows x 64 elems (1 KB).
  int srow = wv * 32 + (L >> 3);
  int sblk = (L & 7) ^ (L >> 3);
  const u16* gA = Ap + (size_t)(m0 + srow) * 512 + sblk * 8;
  const u16* gB = Bp + (size_t)(n0 + srow) * 512 + sblk * 8;

  auto stage = [&](int kt, int buf) {
#pragma unroll
    for (int c = 0; c < 4; ++c) {
      gload_lds16(gA + (size_t)c * 8 * 512 + kt * 64,
                  &lA[buf][(wv * 32 + c * 8) * 64]);
      gload_lds16(gB + (size_t)c * 8 * 512 + kt * 64,
                  &lB[buf][(wv * 32 + c * 8) * 64]);
    }
  };

  v4f acc[8][4] = {};
  int ra = (wm * 128 + colL) * 64;   // + fm*1024
  int rb = (wn * 64 + colL) * 64;    // + fn*1024
  int x0 = ((quad) ^ (colL & 7)) * 8;        // kk=0 col-block (swizzled)
  int x1 = ((4 + quad) ^ (colL & 7)) * 8;    // kk=1

  stage(0, 0);
  stage(1, 1);
  asm volatile("s_waitcnt vmcnt(8)" ::: "memory");   // tile 0 landed
  __builtin_amdgcn_s_barrier();

  for (int kt = 0; kt < 8; ++kt) {
    int buf = kt & 1;
    const u16* pa = &lA[buf][0];
    const u16* pb = &lB[buf][0];
    // kk = 0
    {
      v8s af[8], bf[4];
#pragma unroll
      for (int fm = 0; fm < 8; ++fm) af[fm] = *(const v8s*)&pa[ra + fm * 1024 + x0];
#pragma unroll
      for (int fn = 0; fn < 4; ++fn) bf[fn] = *(const v8s*)&pb[rb + fn * 1024 + x0];
      __builtin_amdgcn_s_setprio(1);
#pragma unroll
      for (int fm = 0; fm < 8; ++fm)
#pragma unroll
        for (int fn = 0; fn < 4; ++fn)
          acc[fm][fn] = __builtin_amdgcn_mfma_f32_16x16x32_bf16(af[fm], bf[fn], acc[fm][fn], 0, 0, 0);
      __builtin_amdgcn_s_setprio(0);
    }
    // kk = 1
    {
      v8s af[8], bf[4];
#pragma unroll
      for (int fm = 0; fm < 8; ++fm) af[fm] = *(const v8s*)&pa[ra + fm * 1024 + x1];
#pragma unroll
      for (int fn = 0; fn < 4; ++fn) bf[fn] = *(const v8s*)&pb[rb + fn * 1024 + x1];
      __builtin_amdgcn_s_setprio(1);
#pragma unroll
      for (int fm = 0; fm < 8; ++fm)
#pragma unroll
        for (int fn = 0; fn < 4; ++fn)
          acc[fm][fn] = __builtin_amdgcn_mfma_f32_16x16x32_bf16(af[fm], bf[fn], acc[fm][fn], 0, 0, 0);
      __builtin_amdgcn_s_setprio(0);
    }
    if (kt < 7) {
      __builtin_amdgcn_s_barrier();          // all waves done reading buf
      if (kt + 2 < 8) {
        stage(kt + 2, buf);                  // overwrite just-freed buffer
        asm volatile("s_waitcnt vmcnt(8)" ::: "memory");  // tile kt+1 done
      } else {
        asm volatile("s_waitcnt vmcnt(0)" ::: "memory");  // drain last tile
      }
      __builtin_amdgcn_s_barrier();          // publish tile kt+1
    }
  }

  // epilogue: row = m0 + wm*128 + fm*16 + quad*4 + r ; col = n0 + wn*64 + fn*16 + colL
#pragma unroll
  for (int fm = 0; fm < 8; ++fm) {
#pragma unroll
    for (int r = 0; r < 4; ++r) {
      int row = m0 + wm * 128 + fm * 16 + quad * 4 + r;
      if (row < Mstore) {
#pragma unroll
        for (int fn = 0; fn < 4; ++fn) {
          int col = n0 + wn * 64 + fn * 16 + colL;
          if (F32OUT) ((float*)Cp)[(size_t)row * NSTR + col] = acc[fm][fn][r];
          else        ((u16*)Cp)[(size_t)row * NSTR + col] = f2b(acc[fm][fn][r]);
        }
      }
    }
  }
}

// ---------------------------------------------------------------------------
// K1: QKV GEMM (R3, measured win). Grid (142,6): x=0..140 vid M-tiles,
// x==141 txt (txt_b zero-padded to 256 rows, stores masked to 128).
__global__ __launch_bounds__(512, 2) void k_gemm_qkv(const u16* __restrict__ A,
                                                     const u16* __restrict__ Bt,
                                                     u16* __restrict__ Cv,
                                                     const u16* __restrict__ At,
                                                     const u16* __restrict__ Btt,
                                                     u16* __restrict__ Ct) {
  int mt = blockIdx.x, nt = blockIdx.y;
  if (mt < 141) gemm256<1536, 0>(A,  Bt,  Cv, mt * 256, nt * 256, MPAD);
  else          gemm256<1536, 0>(At, Btt, Ct, 0,        nt * 256, 128);
}

// ---------------------------------------------------------------------------
// K2: RoPE + window gather (x<45) fused with txt broadcast fill (x>=45).
// Vt written in the position-permuted layout (see header comment).
// Q is pre-scaled by 1/sqrt(128)*log2(e) so k_attn's softmax is exp2-direct.
// RoPE cos/sin from the precomputed per-axis tables (L1-resident, 25 KB).
__global__ __launch_bounds__(256) void k_ropegather(const u16* __restrict__ qkv,
                                                    const u16* __restrict__ qkvt,
                                                    u16* __restrict__ Q,
                                                    u16* __restrict__ K,
                                                    u16* __restrict__ Vt,
                                                    const float2* __restrict__ tbl) {
  __shared__ u16 lv[512 * 18];
  int t = threadIdx.x;
  int w = blockIdx.y;
  if (blockIdx.x >= 45) {
    // ---- txt fill for window w: 4 blocks x 256 threads = 1024 ----
    int tb = (blockIdx.x - 45) * 256 + t;
#pragma unroll
    for (int k = 0; k < 4; ++k) {           // Q/K octets
      int o = tb * 4 + k;
      int h = o >> 10, p64 = (o >> 4) & 63, c8 = o & 15;
      U8 q, kk;
      q.u  = *(const uint4*)&qkvt[(size_t)p64 * 1536 + h * 128 + c8 * 8];
      kk.u = *(const uint4*)&qkvt[(size_t)p64 * 1536 + 512 + h * 128 + c8 * 8];
#pragma unroll
      for (int j = 0; j < 8; ++j) q.s[j] = f2b(b2f(q.s[j]) * QK_SCALE_L2E);
      size_t base = (((size_t)w * 4 + h) * SP + WSZ + p64) * 128 + c8 * 8;
      *(uint4*)&Q[base] = q.u;
      *(uint4*)&K[base] = kk.u;
    }
#pragma unroll
    for (int k = 0; k < 8; ++k) {           // V runs of 4 (permuted layout)
      int vr = tb * 8 + k;
      int h = vr >> 11, ch = (vr >> 4) & 127, run = vr & 15;
      int l0 = WSZ + run * 4;
      uint2 o;
      u16* os = (u16*)&o;
#pragma unroll
      for (int j = 0; j < 4; ++j)
        os[j] = qkvt[(size_t)(l0 - WSZ + j) * 1536 + 1024 + h * 128 + ch];
      *(uint2*)&Vt[(((size_t)w * 4 + h) * 128 + ch) * SP + vperm4(l0)] = o;
    }
    return;
  }
  // ---- rope + gather ----
  int pt = blockIdx.x;
  int p_local = t >> 4;
  int p = pt * 16 + p_local;               // < 720
  int iw = w / 10; int r10 = w - iw * 10; int ih = r10 >> 1; int it = r10 & 1;
  int dt = p / 144; int rem = p - dt * 144; int dh = rem >> 4; int dw = rem & 15;
  int tt = it * 5 + dt, hh = ih * 9 + dh, wx = iw * 16 + dw;
  int n = tt * 3600 + hh * 80 + wx;
  const size_t qrow = (size_t)n * 1536;
#pragma unroll
  for (int it2 = 0; it2 < 12; ++it2) {
    int oct = it2 * 16 + (t & 15);
    int col = oct * 8;
    U8 x; x.u = *(const uint4*)&qkv[qrow + col];
    if (col < 1024) {                      // Q or K -> rope (table lookup)
      int cc = col & 511; int h = cc >> 7; int ch = cc & 127;
      int bi;
      if (ch < 32)      bi = tt * 16 + (ch >> 1);
      else if (ch < 80) bi = TBL_H + hh * 24 + ((ch - 32) >> 1);
      else              bi = TBL_W + wx * 24 + ((ch - 80) >> 1);
      bool isQ = col < 512;
      float sc = isQ ? QK_SCALE_L2E : 1.0f;
      U8 o;
#pragma unroll
      for (int pr = 0; pr < 4; ++pr) {
        float2 cs = tbl[bi + pr];
        float x0 = b2f(x.s[2 * pr]), x1 = b2f(x.s[2 * pr + 1]);
        o.s[2 * pr]     = f2b((x0 * cs.x - x1 * cs.y) * sc);
        o.s[2 * pr + 1] = f2b((x1 * cs.x + x0 * cs.y) * sc);
      }
      u16* dst = isQ ? Q : K;
      *(uint4*)&dst[(((size_t)w * 4 + h) * SP + p) * 128 + ch] = o.u;
    } else {                               // V -> LDS for transpose
      int cv = col - 1024;
#pragma unroll
      for (int j = 0; j < 8; ++j) lv[(cv + j) * 18 + p_local] = x.s[j];
    }
  }
  __syncthreads();
#pragma unroll
  for (int it3 = 0; it3 < 4; ++it3) {
    int slot = it3 * 256 + t; int cv = slot >> 1; int half = slot & 1;
    U8 o;
#pragma unroll
    for (int j = 0; j < 8; ++j) o.s[j] = lv[cv * 18 + half * 8 + j];
    int h = cv >> 7, ch = cv & 127;
    int P0 = pt * 16 + half * 8;           // logical pos run start (8-aligned)
    size_t base = (((size_t)w * 4 + h) * 128 + ch) * SP;
    *(uint2*)&Vt[base + vperm4(P0)]     = make_uint2(o.u.x, o.u.y);
    *(uint2*)&Vt[base + vperm4(P0 + 4)] = make_uint2(o.u.z, o.u.w);
  }
}

// ---------------------------------------------------------------------------
// K4: flash attention (R1/R3 structure — measured local optimum, 113.5 us).
// Per (w,h,qt): 4 waves x 32 q. S^T = mfma(K_frag, Q_frag); P^T packed from
// own-lane regs; PV uses the sigma k-order via position-permuted Vt.
// 2-phase pipeline: dbuf K/V LDS, prefetch kt+1 before computing kt, one
// __syncthreads per iteration. Dead (all-pad) waves stage+barrier only.
// Grid: logical flat 1400, XCD-swizzled; launched as 704+696 (base offset,
// multiple of 8 keeps id&7 == hw XCD) so other kernels appear in top-5.
__global__ __launch_bounds__(256) void k_attn(const u16* __restrict__ Q,
                                              const u16* __restrict__ Kb,
                                              const u16* __restrict__ Vt,
                                              u16* __restrict__ outr,
                                              float* __restrict__ txt_acc,
                                              int base) {
  __shared__ u16 lK[2][4 * 64 * 32];   // [buf][kc][key 64][ch 32]
  __shared__ u16 lV[2][2 * 128 * 32];  // [buf][kc2][ch 128][perm-pos 32]
  int t = threadIdx.x, wv = t >> 6, L = t & 63;
  int id = blockIdx.x + base;
  int xcd = id & 7, sidx = id >> 3;
  int whg = sidx / 7;  int qt = sidx - whg * 7;
  int wh = whg * 8 + xcd;
  int w = wh >> 2, h = wh & 3;
  size_t whq = ((size_t)wh) * SP * 128;
  int q0 = qt * 128 + wv * 32;
  bool live = q0 < SEQ;               // all-pad waves skip compute entirely
  if (q0 > 800) q0 = 800;             // keep qf loads in-bounds
  int colL = L & 15, quad = L >> 4;
  v8s qf[2][4];
#pragma unroll
  for (int s = 0; s < 2; ++s) {
    const u16* qp = Q + whq + (size_t)(q0 + s * 16 + colL) * 128 + quad * 8;
#pragma unroll
    for (int kc = 0; kc < 4; ++kc) qf[s][kc] = *(const v8s*)(qp + kc * 32);
  }
  float li[2] = {0.f, 0.f};
  v4f O[2][8] = {};

  // stage K/V tile kt into buffer buf (8 global_load_lds per wave, 32/block)
  auto stage = [&](int kt, int buf) {
#pragma unroll
    for (int pass = 0; pass < 4; ++pass) {
      int cr = wv * 64 + pass * 16 + (L >> 2);
      int kc = cr >> 6, row = cr & 63;          // K tile: [kc][row][32]
      gload_lds16(Kb + whq + (size_t)(kt * 64 + row) * 128 + kc * 32 + (L & 3) * 8,
                  (u16*)&lK[buf][0] + (size_t)(wv * 64 + pass * 16) * 32);
      int kc2 = cr >> 7, ch = cr & 127;          // V tile: [kc2][ch][32]
      gload_lds16(Vt + whq + (size_t)ch * SP + kt * 64 + kc2 * 32 + (L & 3) * 8,
                  (u16*)&lV[buf][0] + (size_t)(wv * 64 + pass * 16) * 32);
    }
  };

  stage(0, 0);
  __syncthreads();                     // drain prologue stage

  for (int kt = 0; kt < 13; ++kt) {
    int cur = kt & 1;
    if (kt < 12) stage(kt + 1, cur ^ 1);   // prefetch overlaps compute below

    if (live) {
      const u16* lKc = &lK[cur][0];
      const u16* lVc = &lV[cur][0];

      // S^T = K Q^T  (scale*log2e pre-folded into Q); col=q, row=key
      v4f ST[2][4] = {};
      __builtin_amdgcn_s_setprio(1);
#pragma unroll
      for (int kc = 0; kc < 4; ++kc) {
#pragma unroll
        for (int nbk = 0; nbk < 4; ++nbk) {
          v8s kf = *(const v8s*)&lKc[(kc * 64 + nbk * 16 + colL) * 32 + quad * 8];
          ST[0][nbk] = __builtin_amdgcn_mfma_f32_16x16x32_bf16(kf, qf[0][kc], ST[0][nbk], 0, 0, 0);
          ST[1][nbk] = __builtin_amdgcn_mfma_f32_16x16x32_bf16(kf, qf[1][kc], ST[1][nbk], 0, 0, 0);
        }
      }
      __builtin_amdgcn_s_setprio(0);

      // exp2 (wave-uniform masking: only kt==12, nbk>0 invalid), truncate to
      // bf16, accumulate li from truncated values, pack B-frags (P^T).
      union { v8s v; u32 wd[4]; } Bf[2][2];   // [kc2][s]
#pragma unroll
      for (int s = 0; s < 2; ++s) {
#pragma unroll
        for (int nbk = 0; nbk < 4; ++nbk) {
          float ev[4];
          if (kt * 64 + nbk * 16 < SEQ) {
#pragma unroll
            for (int r = 0; r < 4; ++r) {
              float e = __builtin_amdgcn_exp2f(ST[s][nbk][r]);
              u32 tb = __builtin_bit_cast(u32, e) & 0xFFFF0000u;
              float tf = __builtin_bit_cast(float, tb);
              li[s] += tf;
              ev[r] = tf;
            }
          } else {
#pragma unroll
            for (int r = 0; r < 4; ++r) ev[r] = 0.f;
          }
          Bf[nbk >> 1][s].wd[(nbk & 1) * 2 + 0] = pkhi(ev[0], ev[1]);
          Bf[nbk >> 1][s].wd[(nbk & 1) * 2 + 1] = pkhi(ev[2], ev[3]);
        }
      }

      // O^T += V^T P^T  (sigma k-order; A one b128 from permuted lV, B regs)
      __builtin_amdgcn_s_setprio(1);
#pragma unroll
      for (int kc2 = 0; kc2 < 2; ++kc2) {
#pragma unroll
        for (int nbo = 0; nbo < 8; ++nbo) {
          v8s af = *(const v8s*)&lVc[(kc2 * 128 + nbo * 16 + colL) * 32 + quad * 8];
          O[0][nbo] = __builtin_amdgcn_mfma_f32_16x16x32_bf16(af, Bf[kc2][0].v, O[0][nbo], 0, 0, 0);
          O[1][nbo] = __builtin_amdgcn_mfma_f32_16x16x32_bf16(af, Bf[kc2][1].v, O[1][nbo], 0, 0, 0);
        }
      }
      __builtin_amdgcn_s_setprio(0);
    }

    __syncthreads();   // drains prefetch (vmcnt0) + guards buffer reuse
  }

  if (!live) return;

  // li: reduce across quads (lanes c, c+16, c+32, c+48)
  float linv[2];
#pragma unroll
  for (int s = 0; s < 2; ++s) {
    float v = li[s];
    v += __shfl_xor(v, 16);
    v += __shfl_xor(v, 32);
    linv[s] = 1.f / v;
  }

  // epilogue: lane holds channels nbo*16+quad*4+{0..3} of q row (q0+s*16+colL)
  int iw = w / 10; int r10 = w - iw * 10; int ih = r10 >> 1; int it = r10 & 1;
#pragma unroll
  for (int s = 0; s < 2; ++s) {
    int p = q0 + s * 16 + colL;
    if (p < WSZ) {
      int dt = p / 144; int rem = p - dt * 144; int dh = rem >> 4; int dw = rem & 15;
      int n = (it * 5 + dt) * 3600 + (ih * 9 + dh) * 80 + iw * 16 + dw;
      size_t rowbase = (size_t)n * DM + h * 128 + quad * 4;
#pragma unroll
      for (int nbo = 0; nbo < 8; ++nbo) {
        uint2 st;
        st.x = (u32)f2b(O[s][nbo][0] * linv[s]) | ((u32)f2b(O[s][nbo][1] * linv[s]) << 16);
        st.y = (u32)f2b(O[s][nbo][2] * linv[s]) | ((u32)f2b(O[s][nbo][3] * linv[s]) << 16);
        *(uint2*)&outr[rowbase + nbo * 16] = st;
      }
    } else if (p < SEQ) {
      size_t rb = (size_t)(p - WSZ) * DM + h * 128 + quad * 4;
#pragma unroll
      for (int nbo = 0; nbo < 8; ++nbo)
#pragma unroll
        for (int r = 0; r < 4; ++r)
          atomicAdd(&txt_acc[rb + nbo * 16 + r], O[s][nbo][r] * linv[s] * 0.02f);
    }
  }
}

// ---------------------------------------------------------------------------
// K5: out GEMM — 256x256 pipelined structure (same as QKV GEMM), f32 out,
// rows masked at N_VID. Grid (157,2): x=0..140 vid M-tiles (y = N-tile of
// 512); x=141..156 txt GEMV blocks: b=(x-141)*2+y in 0..31, rows 2b,2b+1.
__global__ __launch_bounds__(512, 2) void k_gemm_out(const u16* __restrict__ A,
                                                     const u16* __restrict__ Bt,
                                                     float* __restrict__ out,
                                                     const float* __restrict__ acc,
                                                     const float* __restrict__ wo) {
  int mt = blockIdx.x, nt = blockIdx.y;
  if (mt < 141) {
    gemm256<512, 1>(A, Bt, out, mt * 256, nt * 256, N_VID);
    return;
  }
  int b = (mt - 141) * 2 + nt;                   // 0..31
  int t = threadIdx.x;
  int r = 2 * b + (t >> 8);                      // 0..63
  int c = t & 255;
  float s0 = 0.f, s1 = 0.f;
  for (int k = 0; k < 512; ++k) {
    float a = acc[r * 512 + k];
    s0 = fmaf(a, wo[k * 512 + c], s0);
    s1 = fmaf(a, wo[k * 512 + c + 256], s1);
  }
  float* ob = out + (size_t)N_VID * DM;
  ob[(size_t)r * 512 + c] = s0;
  ob[(size_t)r * 512 + c + 256] = s1;
}

// ---------------------------------------------------------------------------
extern "C" void kernel_launch(void* const* d_in, const int* in_sizes, int n_in,
                              void* d_out, int out_size, void* d_ws, size_t ws_size,
                              hipStream_t stream) {
  const float* vid       = (const float*)d_in[0];
  const float* txt       = (const float*)d_in[1];
  const float* w_qkv_vid = (const float*)d_in[2];
  const float* w_qkv_txt = (const float*)d_in[3];
  const float* w_out_vid = (const float*)d_in[4];
  const float* w_out_txt = (const float*)d_in[5];
  float* out = (float*)d_out;
  char* ws = (char*)d_ws;

  size_t off = 0;
  u16* vid_b   = (u16*)(ws + off); off += (size_t)MPAD * DM * 2;       // reused as out_rows
  u16* txt_b   = (u16*)(ws + off); off += 256 * DM * 2;                // padded to 256 rows
  u16* wt_qv   = (u16*)(ws + off); off += 1536 * 512 * 2;
  u16* wt_qt   = (u16*)(ws + off); off += 1536 * 512 * 2;
  u16* wt_ov   = (u16*)(ws + off); off += 512 * 512 * 2;
  u16* qkv_v   = (u16*)(ws + off); off += (size_t)MPAD * 1536 * 2;
  u16* qkv_t   = (u16*)(ws + off); off += 128 * 1536 * 2;
  u16* Qb      = (u16*)(ws + off); off += (size_t)NW * 4 * SP * 128 * 2;
  u16* Kb      = (u16*)(ws + off); off += (size_t)NW * 4 * SP * 128 * 2;
  u16* Vtb     = (u16*)(ws + off); off += (size_t)NW * 4 * 128 * SP * 2;
  float* tacc  = (float*)(ws + off); off += 64 * 512 * 4;
  float2* tbl  = (float2*)(ws + off); off += TBL_N * sizeof(float2);
  u16* out_rows = vid_b;   // alias: vid_b dead after QKV GEMM

  hipMemsetAsync(tacc, 0, 64 * 512 * 4, stream);

  k_prep<<<9537, 256, 0, stream>>>(vid, txt, vid_b, txt_b,
                                   w_qkv_vid, w_qkv_txt, w_out_vid,
                                   wt_qv, wt_qt, wt_ov, tbl);

  k_gemm_qkv<<<dim3(142, 6), 512, 0, stream>>>(vid_b, wt_qv, qkv_v,
                                               txt_b, wt_qt, qkv_t);

  k_ropegather<<<dim3(49, 50), 256, 0, stream>>>(qkv_v, qkv_t, Qb, Kb, Vtb, tbl);

  k_attn<<<704, 256, 0, stream>>>(Qb, Kb, Vtb, out_rows, tacc, 0);
  k_attn<<<696, 256, 0, stream>>>(Qb, Kb, Vtb, out_rows, tacc, 704);

  k_gemm_out<<<dim3(157, 2), 512, 0, stream>>>(out_rows, wt_ov, out, tacc, w_out_txt);
}

// Round 8
// 436.846 us; speedup vs baseline: 1.0658x; 1.0658x over previous
//
#include <hip/hip_runtime.h>
#include <hip/hip_bf16.h>

// ---------------------------------------------------------------------------
// NaSwinAttention on MI355X.
// Static problem geometry:
//   T=10,H=45,W=80 -> N_VID=36000, D=512, HEADS=4, HD=128, TXT=64
//   windows: wt=5, wh=9, ww=16 ; nt=2, nh=5, nw=5 -> 50 windows x 720 tokens
//   window id  w = iw*10 + ih*2 + it   (it fastest)
//   pos in win p = dt*144 + dh*16 + dw
//   token      n = (it*5+dt)*3600 + (ih*9+dh)*80 + iw*16 + dw
//   seq per window = 720 + 64 txt = 784, padded to 832 (13*64)
//
// Vt global layout is POSITION-PERMUTED: within each 32-aligned pos chunk,
// physical index e holds logical pos (e>>3)*4 + (e&3) + ((e>>2)&1)*16, so
// k_attn's b128 read at phys [quad*8..+7] yields logical keys
// {quad*4+0..3, 16+quad*4+0..3} = the sigma-order used by the register-P
// PV contraction. Inverse (4-aligned run start l0):
//   phys = (l0 & ~31) + ((l0&15)>>2)*8 + ((l0>>4)&1)*4
//
// R1: attn 2-phase pipeline + dead-wave skip + exp2 (115 us; gain==skip).
// R2: FAILED: 8-wave attn blocks -> barrier lockstep, 145 us. Reverted.
// R3: 256x256 QKV GEMM w/ counted vmcnt pipeline (T4) + swizzle (T2): -12 us.
// R4/R5: FAILED: attn 1-deep sw-pipeline -> occupancy halved, 163 us. Revert.
// R6: out-GEMM ported to 256x256 counted-vmcnt structure: -12.5 us (438 us).
// R7: instrumentation round: k_attn split showed k_gemm_qkv = 91 us with
//     FETCH 119 MB vs 38.5 MB input (A re-streamed per N-tile; grid
//     x-fastest). Split itself cost ~28 us. Rope tables kept (neutral+).
// R8: (a) k_attn merged back to one 1400-block dispatch. (b) k_gemm_qkv
//     flat grid 852 with bijective XCD chunking (m204): consecutive wg on
//     one XCD = all 6 N-tiles of an M-tile -> A-panel read once per XCD,
//     B L2-resident. Expect FETCH ~119->~55 MB, dur 91->~68 us.
// ---------------------------------------------------------------------------

typedef unsigned short u16;
typedef unsigned int   u32;
typedef float v4f __attribute__((ext_vector_type(4)));
typedef short v8s __attribute__((ext_vector_type(8)));

#define N_VID    36000
#define MPAD     36096        // 282*128 = 141*256
#define DM       512
#define NW       50
#define WSZ      720
#define SEQ      784
#define SP       832          // padded seq (13*64)
// 1/sqrt(128) * log2(e): Q pre-scale so attn uses exp2 directly
#define QK_SCALE_L2E 0.12751743f
#define L2THETA  13.287712379549449f   // log2(10000)
// rope table offsets: t-axis [10][16], h-axis [45][24], w-axis [80][24]
#define TBL_H    160
#define TBL_W    1240
#define TBL_N    3160

union U8 { uint4 u; u16 s[8]; };

__device__ __forceinline__ u16 f2b(float f) {
  u32 u = __builtin_bit_cast(u32, f);
  u32 r = (u + 0x7FFFu + ((u >> 16) & 1u)) >> 16;
  return (u16)r;
}
__device__ __forceinline__ float b2f(u16 h) {
  u32 u = ((u32)h) << 16;
  return __builtin_bit_cast(float, u);
}
// pack hi16(lo),hi16(hi) -> u32 (bf16 truncation pack, 1 instr)
__device__ __forceinline__ u32 pkhi(float lo, float hi) {
  return __builtin_amdgcn_perm(__builtin_bit_cast(u32, hi),
                               __builtin_bit_cast(u32, lo), 0x07060302u);
}
// physical index of a 4-aligned logical-position run start (Vt permutation)
__device__ __forceinline__ int vperm4(int l0) {
  return (l0 & ~31) + (((l0 & 15) >> 2) << 3) + (((l0 >> 4) & 1) << 2);
}

__device__ __forceinline__ void gload_lds16(const void* g, void* l) {
  __builtin_amdgcn_global_load_lds(
      (const __attribute__((address_space(1))) void*)g,
      (__attribute__((address_space(3))) void*)l,
      16, 0, 0);
}

// ---------------------------------------------------------------------------
// K0: fused prep. blocks 0..9087: fp32->bf16 convert (vid padded to MPAD,
// txt padded to 256 rows). blocks 9088..9535: weight transpose
// fp32[K][N]->bf16[N][K]. block 9536: rope cos/sin tables.
__global__ __launch_bounds__(256) void k_prep(const float* __restrict__ vid,
                                              const float* __restrict__ txt,
                                              u16* __restrict__ vid_b,
                                              u16* __restrict__ txt_b,
                                              const float* __restrict__ wqv,
                                              const float* __restrict__ wqt,
                                              const float* __restrict__ wov,
                                              u16* __restrict__ o0,
                                              u16* __restrict__ o1,
                                              u16* __restrict__ o2,
                                              float2* __restrict__ tbl) {
  __shared__ u16 lt[64 * 72];
  int t = threadIdx.x;
  if (blockIdx.x < 9088) {
    int id  = blockIdx.x * 256 + t;
    int row = id >> 6, oct = id & 63;
    U8 o;
    if (row < MPAD) {
      if (row < N_VID) {
        const float* s = vid + (size_t)row * DM + oct * 8;
        float4 a = *(const float4*)s, b = *(const float4*)(s + 4);
        o.s[0]=f2b(a.x); o.s[1]=f2b(a.y); o.s[2]=f2b(a.z); o.s[3]=f2b(a.w);
        o.s[4]=f2b(b.x); o.s[5]=f2b(b.y); o.s[6]=f2b(b.z); o.s[7]=f2b(b.w);
      } else { o.u = make_uint4(0,0,0,0); }
      *(uint4*)&vid_b[(size_t)row * DM + oct * 8] = o.u;
    } else {
      int tr = row - MPAD;
      if (tr >= 256) return;
      if (tr < 64) {
        const float* s = txt + (size_t)tr * DM + oct * 8;
        float4 a = *(const float4*)s, b = *(const float4*)(s + 4);
        o.s[0]=f2b(a.x); o.s[1]=f2b(a.y); o.s[2]=f2b(a.z); o.s[3]=f2b(a.w);
        o.s[4]=f2b(b.x); o.s[5]=f2b(b.y); o.s[6]=f2b(b.z); o.s[7]=f2b(b.w);
      } else { o.u = make_uint4(0,0,0,0); }
      *(uint4*)&txt_b[(size_t)tr * DM + oct * 8] = o.u;
    }
    return;
  }
  // ---- transpose / table branch ----
  int b = blockIdx.x - 9088;
  if (b == 448) {
    // rope tables: entry i -> (pos, freq k, axis dinv); cos/sin of pos*inv
    for (int i = t; i < TBL_N; i += 256) {
      int pos, k; float dinv;
      if (i < TBL_H)      { pos = i >> 4;             k = i & 15;          dinv = 1.f / 32.f; }
      else if (i < TBL_W) { int j = i - TBL_H;  pos = j / 24; k = j % 24;  dinv = 1.f / 48.f; }
      else                { int j = i - TBL_W;  pos = j / 24; k = j % 24;  dinv = 1.f / 48.f; }
      float inv = exp2f(-2.f * (float)k * dinv * L2THETA);
      float ang = (float)pos * inv;
      tbl[i] = make_float2(cosf(ang), sinf(ang));
    }
    return;
  }
  const float* src; u16* dst; int N; int tb;
  if (b < 192)      { src = wqv; dst = o0; N = 1536; tb = b; }
  else if (b < 384) { src = wqt; dst = o1; N = 1536; tb = b - 192; }
  else              { src = wov; dst = o2; N = 512;  tb = b - 384; }
  int kt = tb & 7, nt = tb >> 3;
  int k0 = kt * 64, n0 = nt * 64;
#pragma unroll
  for (int pass = 0; pass < 16; ++pass) {
    int kl = pass * 4 + (t >> 6), nl = t & 63;
    float v = src[(size_t)(k0 + kl) * N + n0 + nl];
    lt[nl * 72 + kl] = f2b(v);
  }
  __syncthreads();
#pragma unroll
  for (int pass = 0; pass < 2; ++pass) {
    int slot = pass * 256 + t;
    int nr = slot >> 3, ko = slot & 7;
    U8 o;
#pragma unroll
    for (int j = 0; j < 8; ++j) o.s[j] = lt[nr * 72 + ko * 8 + j];
    *(uint4*)&dst[(size_t)(n0 + nr) * 512 + k0 + ko * 8] = o.u;
  }
}

// ---------------------------------------------------------------------------
// 256x256 tile GEMM body (R3-proven): BK=64, 8 waves (2M x 4N), 512 threads,
// K=512 fixed (8 K-tiles). Double-buffered LDS (128 KB), raw s_barrier +
// counted s_waitcnt vmcnt(8): tile kt+2's 8 loads stay in flight across both
// barriers. XOR col-block swizzle (involution) on global source + ds_read.
// C row stride NSTR; rows >= Mstore masked (f32 or bf16 out via F32OUT).
template <int NSTR, int F32OUT>
__device__ __forceinline__ void gemm256(const u16* __restrict__ Ap,
                                        const u16* __restrict__ Bp,
                                        void* __restrict__ Cp,
                                        int m0, int n0, int Mstore) {
  __shared__ u16 lA[2][256 * 64];
  __shared__ u16 lB[2][256 * 64];
  int t = threadIdx.x, wv = t >> 6, L = t & 63;
  int wm = wv >> 2, wn = wv & 3;                 // 2 x 4 wave grid
  int colL = L & 15, quad = L >> 4;

  // staging: per wave 4 calls/operand, each fills 8 rows x 64 elems (1 KB).
  int srow = wv * 32 + (L >> 3);
  int sblk = (L & 7) ^ (L >> 3);
  const u16* gA = Ap + (size_t)(m0 + srow) * 512 + sblk * 8;
  const u16* gB = Bp + (size_t)(n0 + srow) * 512 + sblk * 8;

  auto stage = [&](int kt, int buf) {
#pragma unroll
    for (int c = 0; c < 4; ++c) {
      gload_lds16(gA + (size_t)c * 8 * 512 + kt * 64,
                  &lA[buf][(wv * 32 + c * 8) * 64]);
      gload_lds16(gB + (size_t)c * 8 * 512 + kt * 64,
                  &lB[buf][(wv * 32 + c * 8) * 64]);
    }
  };

  v4f acc[8][4] = {};
  int ra = (wm * 128 + colL) * 64;   // + fm*1024
  int rb = (wn * 64 + colL) * 64;    // + fn*1024
  int x0 = ((quad) ^ (colL & 7)) * 8;        // kk=0 col-block (swizzled)
  int x1 = ((4 + quad) ^ (colL & 7)) * 8;    // kk=1

  stage(0, 0);
  stage(1, 1);
  asm volatile("s_waitcnt vmcnt(8)" ::: "memory");   // tile 0 landed
  __builtin_amdgcn_s_barrier();

  for (int kt = 0; kt < 8; ++kt) {
    int buf = kt & 1;
    const u16* pa = &lA[buf][0];
    const u16* pb = &lB[buf][0];
    // kk = 0
    {
      v8s af[8], bf[4];
#pragma unroll
      for (int fm = 0; fm < 8; ++fm) af[fm] = *(const v8s*)&pa[ra + fm * 1024 + x0];
#pragma unroll
      for (int fn = 0; fn < 4; ++fn) bf[fn] = *(const v8s*)&pb[rb + fn * 1024 + x0];
      __builtin_amdgcn_s_setprio(1);
#pragma unroll
      for (int fm = 0; fm < 8; ++fm)
#pragma unroll
        for (int fn = 0; fn < 4; ++fn)
          acc[fm][fn] = __builtin_amdgcn_mfma_f32_16x16x32_bf16(af[fm], bf[fn], acc[fm][fn], 0, 0, 0);
      __builtin_amdgcn_s_setprio(0);
    }
    // kk = 1
    {
      v8s af[8], bf[4];
#pragma unroll
      for (int fm = 0; fm < 8; ++fm) af[fm] = *(const v8s*)&pa[ra + fm * 1024 + x1];
#pragma unroll
      for (int fn = 0; fn < 4; ++fn) bf[fn] = *(const v8s*)&pb[rb + fn * 1024 + x1];
      __builtin_amdgcn_s_setprio(1);
#pragma unroll
      for (int fm = 0; fm < 8; ++fm)
#pragma unroll
        for (int fn = 0; fn < 4; ++fn)
          acc[fm][fn] = __builtin_amdgcn_mfma_f32_16x16x32_bf16(af[fm], bf[fn], acc[fm][fn], 0, 0, 0);
      __builtin_amdgcn_s_setprio(0);
    }
    if (kt < 7) {
      __builtin_amdgcn_s_barrier();          // all waves done reading buf
      if (kt + 2 < 8) {
        stage(kt + 2, buf);                  // overwrite just-freed buffer
        asm volatile("s_waitcnt vmcnt(8)" ::: "memory");  // tile kt+1 done
      } else {
        asm volatile("s_waitcnt vmcnt(0)" ::: "memory");  // drain last tile
      }
      __builtin_amdgcn_s_barrier();          // publish tile kt+1
    }
  }

  // epilogue: row = m0 + wm*128 + fm*16 + quad*4 + r ; col = n0 + wn*64 + fn*16 + colL
#pragma unroll
  for (int fm = 0; fm < 8; ++fm) {
#pragma unroll
    for (int r = 0; r < 4; ++r) {
      int row = m0 + wm * 128 + fm * 16 + quad * 4 + r;
      if (row < Mstore) {
#pragma unroll
        for (int fn = 0; fn < 4; ++fn) {
          int col = n0 + wn * 64 + fn * 16 + colL;
          if (F32OUT) ((float*)Cp)[(size_t)row * NSTR + col] = acc[fm][fn][r];
          else        ((u16*)Cp)[(size_t)row * NSTR + col] = f2b(acc[fm][fn][r]);
        }
      }
    }
  }
}

// ---------------------------------------------------------------------------
// K1: QKV GEMM. Flat grid 852 (= 142 M-tiles x 6 N-tiles), bijective
// XCD chunking (852 = 8*106 + 4): XCD x gets a contiguous wg-chunk, so the
// 6 N-tiles of each M-tile run on ONE XCD back-to-back -> A-panel (256 KB)
// is fetched into that XCD's L2 once and reused 6x; B (1.5 MB) L2-resident.
// mt==141 is the txt GEMM (txt_b zero-padded to 256 rows, stores masked).
__global__ __launch_bounds__(512, 2) void k_gemm_qkv(const u16* __restrict__ A,
                                                     const u16* __restrict__ Bt,
                                                     u16* __restrict__ Cv,
                                                     const u16* __restrict__ At,
                                                     const u16* __restrict__ Btt,
                                                     u16* __restrict__ Ct) {
  int id = blockIdx.x;
  int xcd = id & 7, orig = id >> 3;
  int wg = (xcd < 4 ? xcd * 107 : 428 + (xcd - 4) * 106) + orig;
  int mt = wg / 6, nt = wg - mt * 6;
  if (mt < 141) gemm256<1536, 0>(A,  Bt,  Cv, mt * 256, nt * 256, MPAD);
  else          gemm256<1536, 0>(At, Btt, Ct, 0,        nt * 256, 128);
}

// ---------------------------------------------------------------------------
// K2: RoPE + window gather (x<45) fused with txt broadcast fill (x>=45).
// Vt written in the position-permuted layout (see header comment).
// Q is pre-scaled by 1/sqrt(128)*log2(e) so k_attn's softmax is exp2-direct.
// RoPE cos/sin from the precomputed per-axis tables (L1-resident, 25 KB).
__global__ __launch_bounds__(256) void k_ropegather(const u16* __restrict__ qkv,
                                                    const u16* __restrict__ qkvt,
                                                    u16* __restrict__ Q,
                                                    u16* __restrict__ K,
                                                    u16* __restrict__ Vt,
                                                    const float2* __restrict__ tbl) {
  __shared__ u16 lv[512 * 18];
  int t = threadIdx.x;
  int w = blockIdx.y;
  if (blockIdx.x >= 45) {
    // ---- txt fill for window w: 4 blocks x 256 threads = 1024 ----
    int tb = (blockIdx.x - 45) * 256 + t;
#pragma unroll
    for (int k = 0; k < 4; ++k) {           // Q/K octets
      int o = tb * 4 + k;
      int h = o >> 10, p64 = (o >> 4) & 63, c8 = o & 15;
      U8 q, kk;
      q.u  = *(const uint4*)&qkvt[(size_t)p64 * 1536 + h * 128 + c8 * 8];
      kk.u = *(const uint4*)&qkvt[(size_t)p64 * 1536 + 512 + h * 128 + c8 * 8];
#pragma unroll
      for (int j = 0; j < 8; ++j) q.s[j] = f2b(b2f(q.s[j]) * QK_SCALE_L2E);
      size_t base = (((size_t)w * 4 + h) * SP + WSZ + p64) * 128 + c8 * 8;
      *(uint4*)&Q[base] = q.u;
      *(uint4*)&K[base] = kk.u;
    }
#pragma unroll
    for (int k = 0; k < 8; ++k) {           // V runs of 4 (permuted layout)
      int vr = tb * 8 + k;
      int h = vr >> 11, ch = (vr >> 4) & 127, run = vr & 15;
      int l0 = WSZ + run * 4;
      uint2 o;
      u16* os = (u16*)&o;
#pragma unroll
      for (int j = 0; j < 4; ++j)
        os[j] = qkvt[(size_t)(l0 - WSZ + j) * 1536 + 1024 + h * 128 + ch];
      *(uint2*)&Vt[(((size_t)w * 4 + h) * 128 + ch) * SP + vperm4(l0)] = o;
    }
    return;
  }
  // ---- rope + gather ----
  int pt = blockIdx.x;
  int p_local = t >> 4;
  int p = pt * 16 + p_local;               // < 720
  int iw = w / 10; int r10 = w - iw * 10; int ih = r10 >> 1; int it = r10 & 1;
  int dt = p / 144; int rem = p - dt * 144; int dh = rem >> 4; int dw = rem & 15;
  int tt = it * 5 + dt, hh = ih * 9 + dh, wx = iw * 16 + dw;
  int n = tt * 3600 + hh * 80 + wx;
  const size_t qrow = (size_t)n * 1536;
#pragma unroll
  for (int it2 = 0; it2 < 12; ++it2) {
    int oct = it2 * 16 + (t & 15);
    int col = oct * 8;
    U8 x; x.u = *(const uint4*)&qkv[qrow + col];
    if (col < 1024) {                      // Q or K -> rope (table lookup)
      int cc = col & 511; int h = cc >> 7; int ch = cc & 127;
      int bi;
      if (ch < 32)      bi = tt * 16 + (ch >> 1);
      else if (ch < 80) bi = TBL_H + hh * 24 + ((ch - 32) >> 1);
      else              bi = TBL_W + wx * 24 + ((ch - 80) >> 1);
      bool isQ = col < 512;
      float sc = isQ ? QK_SCALE_L2E : 1.0f;
      U8 o;
#pragma unroll
      for (int pr = 0; pr < 4; ++pr) {
        float2 cs = tbl[bi + pr];
        float x0 = b2f(x.s[2 * pr]), x1 = b2f(x.s[2 * pr + 1]);
        o.s[2 * pr]     = f2b((x0 * cs.x - x1 * cs.y) * sc);
        o.s[2 * pr + 1] = f2b((x1 * cs.x + x0 * cs.y) * sc);
      }
      u16* dst = isQ ? Q : K;
      *(uint4*)&dst[(((size_t)w * 4 + h) * SP + p) * 128 + ch] = o.u;
    } else {                               // V -> LDS for transpose
      int cv = col - 1024;
#pragma unroll
      for (int j = 0; j < 8; ++j) lv[(cv + j) * 18 + p_local] = x.s[j];
    }
  }
  __syncthreads();
#pragma unroll
  for (int it3 = 0; it3 < 4; ++it3) {
    int slot = it3 * 256 + t; int cv = slot >> 1; int half = slot & 1;
    U8 o;
#pragma unroll
    for (int j = 0; j < 8; ++j) o.s[j] = lv[cv * 18 + half * 8 + j];
    int h = cv >> 7, ch = cv & 127;
    int P0 = pt * 16 + half * 8;           // logical pos run start (8-aligned)
    size_t base = (((size_t)w * 4 + h) * 128 + ch) * SP;
    *(uint2*)&Vt[base + vperm4(P0)]     = make_uint2(o.u.x, o.u.y);
    *(uint2*)&Vt[base + vperm4(P0 + 4)] = make_uint2(o.u.z, o.u.w);
  }
}

// ---------------------------------------------------------------------------
// K4: flash attention (R1/R3 structure — measured local optimum, 113.5 us).
// Per (w,h,qt): 4 waves x 32 q. S^T = mfma(K_frag, Q_frag); P^T packed from
// own-lane regs; PV uses the sigma k-order via position-permuted Vt.
// 2-phase pipeline: dbuf K/V LDS, prefetch kt+1 before computing kt, one
// __syncthreads per iteration. Dead (all-pad) waves stage+barrier only.
// Grid flat 1400, XCD-swizzled so all 7 qt blocks of one (w,h) share id%8.
__global__ __launch_bounds__(256) void k_attn(const u16* __restrict__ Q,
                                              const u16* __restrict__ Kb,
                                              const u16* __restrict__ Vt,
                                              u16* __restrict__ outr,
                                              float* __restrict__ txt_acc) {
  __shared__ u16 lK[2][4 * 64 * 32];   // [buf][kc][key 64][ch 32]
  __shared__ u16 lV[2][2 * 128 * 32];  // [buf][kc2][ch 128][perm-pos 32]
  int t = threadIdx.x, wv = t >> 6, L = t & 63;
  int id = blockIdx.x;
  int xcd = id & 7, sidx = id >> 3;
  int whg = sidx / 7;  int qt = sidx - whg * 7;
  int wh = whg * 8 + xcd;
  int w = wh >> 2, h = wh & 3;
  size_t whq = ((size_t)wh) * SP * 128;
  int q0 = qt * 128 + wv * 32;
  bool live = q0 < SEQ;               // all-pad waves skip compute entirely
  if (q0 > 800) q0 = 800;             // keep qf loads in-bounds
  int colL = L & 15, quad = L >> 4;
  v8s qf[2][4];
#pragma unroll
  for (int s = 0; s < 2; ++s) {
    const u16* qp = Q + whq + (size_t)(q0 + s * 16 + colL) * 128 + quad * 8;
#pragma unroll
    for (int kc = 0; kc < 4; ++kc) qf[s][kc] = *(const v8s*)(qp + kc * 32);
  }
  float li[2] = {0.f, 0.f};
  v4f O[2][8] = {};

  // stage K/V tile kt into buffer buf (8 global_load_lds per wave, 32/block)
  auto stage = [&](int kt, int buf) {
#pragma unroll
    for (int pass = 0; pass < 4; ++pass) {
      int cr = wv * 64 + pass * 16 + (L >> 2);
      int kc = cr >> 6, row = cr & 63;          // K tile: [kc][row][32]
      gload_lds16(Kb + whq + (size_t)(kt * 64 + row) * 128 + kc * 32 + (L & 3) * 8,
                  (u16*)&lK[buf][0] + (size_t)(wv * 64 + pass * 16) * 32);
      int kc2 = cr >> 7, ch = cr & 127;          // V tile: [kc2][ch][32]
      gload_lds16(Vt + whq + (size_t)ch * SP + kt * 64 + kc2 * 32 + (L & 3) * 8,
                  (u16*)&lV[buf][0] + (size_t)(wv * 64 + pass * 16) * 32);
    }
  };

  stage(0, 0);
  __syncthreads();                     // drain prologue stage

  for (int kt = 0; kt < 13; ++kt) {
    int cur = kt & 1;
    if (kt < 12) stage(kt + 1, cur ^ 1);   // prefetch overlaps compute below

    if (live) {
      const u16* lKc = &lK[cur][0];
      const u16* lVc = &lV[cur][0];

      // S^T = K Q^T  (scale*log2e pre-folded into Q); col=q, row=key
      v4f ST[2][4] = {};
      __builtin_amdgcn_s_setprio(1);
#pragma unroll
      for (int kc = 0; kc < 4; ++kc) {
#pragma unroll
        for (int nbk = 0; nbk < 4; ++nbk) {
          v8s kf = *(const v8s*)&lKc[(kc * 64 + nbk * 16 + colL) * 32 + quad * 8];
          ST[0][nbk] = __builtin_amdgcn_mfma_f32_16x16x32_bf16(kf, qf[0][kc], ST[0][nbk], 0, 0, 0);
          ST[1][nbk] = __builtin_amdgcn_mfma_f32_16x16x32_bf16(kf, qf[1][kc], ST[1][nbk], 0, 0, 0);
        }
      }
      __builtin_amdgcn_s_setprio(0);

      // exp2 (wave-uniform masking: only kt==12, nbk>0 invalid), truncate to
      // bf16, accumulate li from truncated values, pack B-frags (P^T).
      union { v8s v; u32 wd[4]; } Bf[2][2];   // [kc2][s]
#pragma unroll
      for (int s = 0; s < 2; ++s) {
#pragma unroll
        for (int nbk = 0; nbk < 4; ++nbk) {
          float ev[4];
          if (kt * 64 + nbk * 16 < SEQ) {
#pragma unroll
            for (int r = 0; r < 4; ++r) {
              float e = __builtin_amdgcn_exp2f(ST[s][nbk][r]);
              u32 tb = __builtin_bit_cast(u32, e) & 0xFFFF0000u;
              float tf = __builtin_bit_cast(float, tb);
              li[s] += tf;
              ev[r] = tf;
            }
          } else {
#pragma unroll
            for (int r = 0; r < 4; ++r) ev[r] = 0.f;
          }
          Bf[nbk >> 1][s].wd[(nbk & 1) * 2 + 0] = pkhi(ev[0], ev[1]);
          Bf[nbk >> 1][s].wd[(nbk & 1) * 2 + 1] = pkhi(ev[2], ev[3]);
        }
      }

      // O^T += V^T P^T  (sigma k-order; A one b128 from permuted lV, B regs)
      __builtin_amdgcn_s_setprio(1);
#pragma unroll
      for (int kc2 = 0; kc2 < 2; ++kc2) {
#pragma unroll
        for (int nbo = 0; nbo < 8; ++nbo) {
          v8s af = *(const v8s*)&lVc[(kc2 * 128 + nbo * 16 + colL) * 32 + quad * 8];
          O[0][nbo] = __builtin_amdgcn_mfma_f32_16x16x32_bf16(af, Bf[kc2][0].v, O[0][nbo], 0, 0, 0);
          O[1][nbo] = __builtin_amdgcn_mfma_f32_16x16x32_bf16(af, Bf[kc2][1].v, O[1][nbo], 0, 0, 0);
        }
      }
      __builtin_amdgcn_s_setprio(0);
    }

    __syncthreads();   // drains prefetch (vmcnt0) + guards buffer reuse
  }

  if (!live) return;

  // li: reduce across quads (lanes c, c+16, c+32, c+48)
  float linv[2];
#pragma unroll
  for (int s = 0; s < 2; ++s) {
    float v = li[s];
    v += __shfl_xor(v, 16);
    v += __shfl_xor(v, 32);
    linv[s] = 1.f / v;
  }

  // epilogue: lane holds channels nbo*16+quad*4+{0..3} of q row (q0+s*16+colL)
  int iw = w / 10; int r10 = w - iw * 10; int ih = r10 >> 1; int it = r10 & 1;
#pragma unroll
  for (int s = 0; s < 2; ++s) {
    int p = q0 + s * 16 + colL;
    if (p < WSZ) {
      int dt = p / 144; int rem = p - dt * 144; int dh = rem >> 4; int dw = rem & 15;
      int n = (it * 5 + dt) * 3600 + (ih * 9 + dh) * 80 + iw * 16 + dw;
      size_t rowbase = (size_t)n * DM + h * 128 + quad * 4;
#pragma unroll
      for (int nbo = 0; nbo < 8; ++nbo) {
        uint2 st;
        st.x = (u32)f2b(O[s][nbo][0] * linv[s]) | ((u32)f2b(O[s][nbo][1] * linv[s]) << 16);
        st.y = (u32)f2b(O[s][nbo][2] * linv[s]) | ((u32)f2b(O[s][nbo][3] * linv[s]) << 16);
        *(uint2*)&outr[rowbase + nbo * 16] = st;
      }
    } else if (p < SEQ) {
      size_t rb = (size_t)(p - WSZ) * DM + h * 128 + quad * 4;
#pragma unroll
      for (int nbo = 0; nbo < 8; ++nbo)
#pragma unroll
        for (int r = 0; r < 4; ++r)
          atomicAdd(&txt_acc[rb + nbo * 16 + r], O[s][nbo][r] * linv[s] * 0.02f);
    }
  }
}

// ---------------------------------------------------------------------------
// K5: out GEMM — 256x256 pipelined structure (same as QKV GEMM), f32 out,
// rows masked at N_VID. Grid (157,2): x=0..140 vid M-tiles (y = N-tile of
// 512); x=141..156 txt GEMV blocks: b=(x-141)*2+y in 0..31, rows 2b,2b+1.
__global__ __launch_bounds__(512, 2) void k_gemm_out(const u16* __restrict__ A,
                                                     const u16* __restrict__ Bt,
                                                     float* __restrict__ out,
                                                     const float* __restrict__ acc,
                                                     const float* __restrict__ wo) {
  int mt = blockIdx.x, nt = blockIdx.y;
  if (mt < 141) {
    gemm256<512, 1>(A, Bt, out, mt * 256, nt * 256, N_VID);
    return;
  }
  int b = (mt - 141) * 2 + nt;                   // 0..31
  int t = threadIdx.x;
  int r = 2 * b + (t >> 8);                      // 0..63
  int c = t & 255;
  float s0 = 0.f, s1 = 0.f;
  for (int k = 0; k < 512; ++k) {
    float a = acc[r * 512 + k];
    s0 = fmaf(a, wo[k * 512 + c], s0);
    s1 = fmaf(a, wo[k * 512 + c + 256], s1);
  }
  float* ob = out + (size_t)N_VID * DM;
  ob[(size_t)r * 512 + c] = s0;
  ob[(size_t)r * 512 + c + 256] = s1;
}

// ---------------------------------------------------------------------------
extern "C" void kernel_launch(void* const* d_in, const int* in_sizes, int n_in,
                              void* d_out, int out_size, void* d_ws, size_t ws_size,
                              hipStream_t stream) {
  const float* vid       = (const float*)d_in[0];
  const float* txt       = (const float*)d_in[1];
  const float* w_qkv_vid = (const float*)d_in[2];
  const float* w_qkv_txt = (const float*)d_in[3];
  const float* w_out_vid = (const float*)d_in[4];
  const float* w_out_txt = (const float*)d_in[5];
  float* out = (float*)d_out;
  char* ws = (char*)d_ws;

  size_t off = 0;
  u16* vid_b   = (u16*)(ws + off); off += (size_t)MPAD * DM * 2;       // reused as out_rows
  u16* txt_b   = (u16*)(ws + off); off += 256 * DM * 2;                // padded to 256 rows
  u16* wt_qv   = (u16*)(ws + off); off += 1536 * 512 * 2;
  u16* wt_qt   = (u16*)(ws + off); off += 1536 * 512 * 2;
  u16* wt_ov   = (u16*)(ws + off); off += 512 * 512 * 2;
  u16* qkv_v   = (u16*)(ws + off); off += (size_t)MPAD * 1536 * 2;
  u16* qkv_t   = (u16*)(ws + off); off += 128 * 1536 * 2;
  u16* Qb      = (u16*)(ws + off); off += (size_t)NW * 4 * SP * 128 * 2;
  u16* Kb      = (u16*)(ws + off); off += (size_t)NW * 4 * SP * 128 * 2;
  u16* Vtb     = (u16*)(ws + off); off += (size_t)NW * 4 * 128 * SP * 2;
  float* tacc  = (float*)(ws + off); off += 64 * 512 * 4;
  float2* tbl  = (float2*)(ws + off); off += TBL_N * sizeof(float2);
  u16* out_rows = vid_b;   // alias: vid_b dead after QKV GEMM

  hipMemsetAsync(tacc, 0, 64 * 512 * 4, stream);

  k_prep<<<9537, 256, 0, stream>>>(vid, txt, vid_b, txt_b,
                                   w_qkv_vid, w_qkv_txt, w_out_vid,
                                   wt_qv, wt_qt, wt_ov, tbl);

  k_gemm_qkv<<<852, 512, 0, stream>>>(vid_b, wt_qv, qkv_v,
                                      txt_b, wt_qt, qkv_t);

  k_ropegather<<<dim3(49, 50), 256, 0, stream>>>(qkv_v, qkv_t, Qb, Kb, Vtb, tbl);

  k_attn<<<1400, 256, 0, stream>>>(Qb, Kb, Vtb, out_rows, tacc);

  k_gemm_out<<<dim3(157, 2), 512, 0, stream>>>(out_rows, wt_ov, out, tacc, w_out_txt);
}